// Round 10
// baseline (403.082 us; speedup 1.0000x reference)
//
#include <hip/hip_runtime.h>
#include <hip/hip_bf16.h>

#define N_NODES   50000
#define N_EDGES   800000
#define N_TOT     850000   // edges + self loops
#define N_GRAPHS  256
#define HEADS     8
#define NEG_SLOPE 0.2f

// ------- dense GEMM + fused alpha: H = X@W; asrc/adst = <H, a_src/a_dst> ----
template<int FIN, int FOUT>
__global__ __launch_bounds__(256) void gemm_kernel(const float* __restrict__ X,
                                                   const float* __restrict__ W,
                                                   float* __restrict__ H,
                                                   const float* __restrict__ a_src,
                                                   const float* __restrict__ a_dst,
                                                   float* __restrict__ asrc_o,
                                                   float* __restrict__ adst_o) {
    constexpr int KC    = 32;
    constexpr int THR_F = FOUT / 4;        // threads spanning fout (32 or 16)
    constexpr int NPT   = 64 / (256 / THR_F); // nodes per thread (8 or 4)
    constexpr int XS_S  = 68;              // padded node-stride (16B aligned)
    constexpr int CH    = FOUT / 8;        // channels per head
    __shared__ float xs[KC * XS_S];        // [k][node]
    __shared__ float ws[KC * FOUT];        // [k][fout]
    const int t = threadIdx.x;
    const int node0 = blockIdx.x * 64;
    const int fo  = (t % THR_F) * 4;
    const int ndb = (t / THR_F) * NPT;
    float4 acc[NPT];
#pragma unroll
    for (int i = 0; i < NPT; ++i) acc[i] = make_float4(0.f, 0.f, 0.f, 0.f);

    const int xn = t >> 2, ks = (t & 3) * 8;   // staging roles
    for (int kc = 0; kc < FIN; kc += KC) {
        __syncthreads();
        float4 a0 = make_float4(0.f,0.f,0.f,0.f), a1 = a0;
        if (node0 + xn < N_NODES) {
            const float* xp = X + (size_t)(node0 + xn) * FIN + kc + ks;
            a0 = *(const float4*)xp;
            a1 = *(const float4*)(xp + 4);
        }
        xs[(ks + 0) * XS_S + xn] = a0.x;
        xs[(ks + 1) * XS_S + xn] = a0.y;
        xs[(ks + 2) * XS_S + xn] = a0.z;
        xs[(ks + 3) * XS_S + xn] = a0.w;
        xs[(ks + 4) * XS_S + xn] = a1.x;
        xs[(ks + 5) * XS_S + xn] = a1.y;
        xs[(ks + 6) * XS_S + xn] = a1.z;
        xs[(ks + 7) * XS_S + xn] = a1.w;
        constexpr int WF4 = KC * FOUT / 4 / 256;   // float4 per thread (4 or 2)
        const float4* wsrc = (const float4*)(W + (size_t)kc * FOUT);
        float4* wdst = (float4*)ws;
#pragma unroll
        for (int i = 0; i < WF4; ++i) wdst[t * WF4 + i] = wsrc[t * WF4 + i];
        __syncthreads();
#pragma unroll 4
        for (int k = 0; k < KC; ++k) {
            float4 wv = *(const float4*)(ws + k * FOUT + fo);
#pragma unroll
            for (int q = 0; q < NPT / 4; ++q) {
                float4 xv = *(const float4*)(xs + k * XS_S + ndb + q * 4);
                acc[q*4+0].x += xv.x * wv.x; acc[q*4+0].y += xv.x * wv.y;
                acc[q*4+0].z += xv.x * wv.z; acc[q*4+0].w += xv.x * wv.w;
                acc[q*4+1].x += xv.y * wv.x; acc[q*4+1].y += xv.y * wv.y;
                acc[q*4+1].z += xv.y * wv.z; acc[q*4+1].w += xv.y * wv.w;
                acc[q*4+2].x += xv.z * wv.x; acc[q*4+2].y += xv.z * wv.y;
                acc[q*4+2].z += xv.z * wv.z; acc[q*4+2].w += xv.z * wv.w;
                acc[q*4+3].x += xv.w * wv.x; acc[q*4+3].y += xv.w * wv.y;
                acc[q*4+3].z += xv.w * wv.z; acc[q*4+3].w += xv.w * wv.w;
            }
        }
    }
    const int h   = fo / CH;           // head owning this thread's 4 channels
    const float4 asv = *(const float4*)(a_src + h * CH + (fo % CH));
    const float4 adv = *(const float4*)(a_dst + h * CH + (fo % CH));
    constexpr int LPH = CH / 4;        // threads per head (4 or 2)
#pragma unroll
    for (int i = 0; i < NPT; ++i) {
        int row = node0 + ndb + i;
        if (row < N_NODES) *(float4*)(H + (size_t)row * FOUT + fo) = acc[i];
        float s = acc[i].x*asv.x + acc[i].y*asv.y + acc[i].z*asv.z + acc[i].w*asv.w;
        float d = acc[i].x*adv.x + acc[i].y*adv.y + acc[i].z*adv.z + acc[i].w*adv.w;
        s += __shfl_xor(s, 1, 64);
        d += __shfl_xor(d, 1, 64);
        if (LPH == 4) { s += __shfl_xor(s, 2, 64); d += __shfl_xor(d, 2, 64); }
        if ((t & (LPH - 1)) == 0 && row < N_NODES) {
            asrc_o[row * 8 + h] = s;
            adst_o[row * 8 + h] = d;
        }
    }
}

// ---------------- CSR build (counting sort by dst, int4-vectorized) ---------
// self-loops are NOT counted: scan adds +1/node; scatter writes them at slot 0.
__global__ void hist_kernel(const int* __restrict__ edst, int* __restrict__ cnt) {
    int i = blockIdx.x * blockDim.x + threadIdx.x;
    if (i >= N_EDGES / 4) return;
    int4 d4 = ((const int4*)edst)[i];
    atomicAdd(&cnt[d4.x], 1);
    atomicAdd(&cnt[d4.y], 1);
    atomicAdd(&cnt[d4.z], 1);
    atomicAdd(&cnt[d4.w], 1);
}

// single-block scan of 50000 counters (+1 self-loop each) -> row_ptr;
// also computes per-graph node ranges (gstart) from the sorted batch vector.
__global__ __launch_bounds__(1024) void scan_kernel(const int* __restrict__ cnt,
                                                    int* __restrict__ row_ptr,
                                                    const int* __restrict__ batch,
                                                    int* __restrict__ gstart) {
    constexpr int EPT = 49;              // 1024*49 = 50176 >= N_NODES
    __shared__ int sm[1024];
    const int t = threadIdx.x;
    if (t < N_GRAPHS) {                  // lower_bound(batch, t)
        int lo = 0, hi = N_NODES;
        while (lo < hi) {
            int mid = (lo + hi) >> 1;
            if (batch[mid] < t) lo = mid + 1; else hi = mid;
        }
        gstart[t] = lo;
        if (t == 0) gstart[N_GRAPHS] = N_NODES;
    }
    int base = t * EPT;
    int local[EPT];
    int s = 0;
#pragma unroll
    for (int i = 0; i < EPT; ++i) {
        int idx = base + i;
        int v = (idx < N_NODES) ? (cnt[idx] + 1) : 0;   // +1: self loop
        local[i] = s;
        s += v;
    }
    sm[t] = s;
    __syncthreads();
    for (int off = 1; off < 1024; off <<= 1) {
        int x = (t >= off) ? sm[t - off] : 0;
        __syncthreads();
        sm[t] += x;
        __syncthreads();
    }
    int tbase = sm[t] - s;               // exclusive block prefix
#pragma unroll
    for (int i = 0; i < EPT; ++i) {
        int idx = base + i;
        if (idx < N_NODES) row_ptr[idx] = tbase + local[i];
    }
    if (t == 1023) row_ptr[N_NODES] = N_TOT;
}

// real edges (int4, from slot 1) + self loops (slot 0) in one launch
__global__ void scatter_kernel(const int* __restrict__ esrc, const int* __restrict__ edst,
                               const int* __restrict__ row_ptr, int* __restrict__ cursor,
                               int* __restrict__ edge_src) {
    int i = blockIdx.x * blockDim.x + threadIdx.x;
    if (i < N_EDGES / 4) {
        int4 s4 = ((const int4*)esrc)[i];
        int4 d4 = ((const int4*)edst)[i];
        int p;
        p = row_ptr[d4.x] + 1 + atomicAdd(&cursor[d4.x], 1); edge_src[p] = s4.x;
        p = row_ptr[d4.y] + 1 + atomicAdd(&cursor[d4.y], 1); edge_src[p] = s4.y;
        p = row_ptr[d4.z] + 1 + atomicAdd(&cursor[d4.z], 1); edge_src[p] = s4.z;
        p = row_ptr[d4.w] + 1 + atomicAdd(&cursor[d4.w], 1); edge_src[p] = s4.w;
    } else if (i < N_EDGES / 4 + N_NODES) {
        int d = i - N_EDGES / 4;
        edge_src[row_ptr[d]] = d;        // self loop at slot 0
    }
}

// ------- fused gather: softmax (no max-shift; logits O(1), f32-safe) --------
template<int CH>
__global__ __launch_bounds__(256) void gat_gather_kernel(
        const int* __restrict__ row_ptr, const int* __restrict__ edge_src,
        const float* __restrict__ asrc, const float* __restrict__ adst,
        const float* __restrict__ H, const float* __restrict__ bias,
        float* __restrict__ out) {
    constexpr int LPE   = 2 * CH;    // 32 (CH16) or 16 (CH8)
    constexpr int SPLIT = 64 / LPE;  // 2 or 4
    constexpr int LPH   = CH / 4;    // lanes per head (4 or 2)
    constexpr int HS    = 8 * CH;    // floats per row
    const int n = (blockIdx.x * blockDim.x + threadIdx.x) >> 6;
    if (n >= N_NODES) return;
    const int lane = threadIdx.x & 63;
    const int sub = lane / LPE;
    const int li  = lane & (LPE - 1);
    const int h   = li / LPH;
    const int off = h * CH + (li & (LPH - 1)) * 4;   // float offset in row
    const float adst_h = adst[n * 8 + h];
    const int e0 = row_ptr[n], e1 = row_ptr[n + 1];
    float sum = 0.f;
    float4 acc = make_float4(0.f, 0.f, 0.f, 0.f);
    int e = e0 + sub;
    for (; e + 3 * SPLIT < e1; e += 4 * SPLIT) {
        int s0 = edge_src[e];
        int s1 = edge_src[e + SPLIT];
        int s2 = edge_src[e + 2 * SPLIT];
        int s3 = edge_src[e + 3 * SPLIT];
        float l0 = asrc[s0 * 8 + h] + adst_h;
        float l1 = asrc[s1 * 8 + h] + adst_h;
        float l2 = asrc[s2 * 8 + h] + adst_h;
        float l3 = asrc[s3 * 8 + h] + adst_h;
        float4 h0 = *(const float4*)(H + (size_t)s0 * HS + off);
        float4 h1 = *(const float4*)(H + (size_t)s1 * HS + off);
        float4 h2 = *(const float4*)(H + (size_t)s2 * HS + off);
        float4 h3 = *(const float4*)(H + (size_t)s3 * HS + off);
        l0 = l0 > 0.f ? l0 : NEG_SLOPE * l0;
        l1 = l1 > 0.f ? l1 : NEG_SLOPE * l1;
        l2 = l2 > 0.f ? l2 : NEG_SLOPE * l2;
        l3 = l3 > 0.f ? l3 : NEG_SLOPE * l3;
        float w0 = __expf(l0), w1 = __expf(l1), w2 = __expf(l2), w3 = __expf(l3);
        sum += (w0 + w1) + (w2 + w3);
        acc.x += w0 * h0.x + w1 * h1.x + w2 * h2.x + w3 * h3.x;
        acc.y += w0 * h0.y + w1 * h1.y + w2 * h2.y + w3 * h3.y;
        acc.z += w0 * h0.z + w1 * h1.z + w2 * h2.z + w3 * h3.z;
        acc.w += w0 * h0.w + w1 * h1.w + w2 * h2.w + w3 * h3.w;
    }
    for (; e < e1; e += SPLIT) {        // tail
        int s = edge_src[e];
        float l = asrc[s * 8 + h] + adst_h;
        float4 hv = *(const float4*)(H + (size_t)s * HS + off);
        l = l > 0.f ? l : NEG_SLOPE * l;
        float w = __expf(l);
        sum += w;
        acc.x += w * hv.x;
        acc.y += w * hv.y;
        acc.z += w * hv.z;
        acc.w += w * hv.w;
    }
#pragma unroll
    for (int mask = LPE; mask < 64; mask <<= 1) {
        sum   += __shfl_xor(sum, mask, 64);
        acc.x += __shfl_xor(acc.x, mask, 64);
        acc.y += __shfl_xor(acc.y, mask, 64);
        acc.z += __shfl_xor(acc.z, mask, 64);
        acc.w += __shfl_xor(acc.w, mask, 64);
    }
    float inv = 1.0f / (sum + 1e-16f);
    float4 bv = *(const float4*)(bias + off);
    float4 v;
    v.x = acc.x * inv + bv.x;  v.x = v.x > 0.f ? v.x : expm1f(v.x);
    v.y = acc.y * inv + bv.y;  v.y = v.y > 0.f ? v.y : expm1f(v.y);
    v.z = acc.z * inv + bv.z;  v.z = v.z > 0.f ? v.z : expm1f(v.z);
    v.w = acc.w * inv + bv.w;  v.w = v.w > 0.f ? v.w : expm1f(v.w);
    *(float4*)(out + (size_t)n * HS + off) = v;
}

// ---------------- pool + head (sorted batch -> no atomics) ------------------
__global__ __launch_bounds__(512) void pool_head_kernel(
        const float* __restrict__ act, const int* __restrict__ gstart,
        const float* __restrict__ fc1_w, const float* __restrict__ fc1_b,
        const float* __restrict__ fc2_w, const float* __restrict__ fc2_b,
        float* __restrict__ out) {
    int g = blockIdx.x;
    int t = threadIdx.x;
    int f = t & 127, strip = t >> 7;       // 0..3
    int n0 = gstart[g], n1 = gstart[g + 1];
    float s = 0.f;
    for (int n = n0 + strip; n < n1; n += 4) s += act[(size_t)n * 128 + f];
    __shared__ float sm[4][128];
    __shared__ float zz[10];
    sm[strip][f] = s;
    __syncthreads();
    if (strip == 0) {
        float cnt = (float)(n1 - n0);
        cnt = cnt > 1.f ? cnt : 1.f;
        sm[0][f] = (sm[0][f] + sm[1][f] + sm[2][f] + sm[3][f]) / cnt;
    }
    __syncthreads();
    if (t < 10) {
        float z = fc1_b[t];
        for (int q = 0; q < 128; ++q) z += sm[0][q] * fc1_w[q * 10 + t];
        zz[t] = z > 0.f ? z : 0.f;
    }
    __syncthreads();
    if (t == 0) {
        float o = fc2_b[0];
#pragma unroll
        for (int j = 0; j < 10; ++j) o += zz[j] * fc2_w[j];
        out[g] = o;
    }
}

extern "C" void kernel_launch(void* const* d_in, const int* in_sizes, int n_in,
                              void* d_out, int out_size, void* d_ws, size_t ws_size,
                              hipStream_t stream) {
    const float* x      = (const float*)d_in[0];
    const float* W1     = (const float*)d_in[1];
    const float* a_src1 = (const float*)d_in[2];
    const float* a_dst1 = (const float*)d_in[3];
    const float* b1     = (const float*)d_in[4];
    const float* W2     = (const float*)d_in[5];
    const float* a_src2 = (const float*)d_in[6];
    const float* a_dst2 = (const float*)d_in[7];
    const float* b2     = (const float*)d_in[8];
    const float* W3     = (const float*)d_in[9];
    const float* a_src3 = (const float*)d_in[10];
    const float* a_dst3 = (const float*)d_in[11];
    const float* b3     = (const float*)d_in[12];
    const float* fc1_w  = (const float*)d_in[13];
    const float* fc1_b  = (const float*)d_in[14];
    const float* fc2_w  = (const float*)d_in[15];
    const float* fc2_b  = (const float*)d_in[16];
    const int*   eidx   = (const int*)d_in[17];
    const int*   batch  = (const int*)d_in[18];
    const int* esrc = eidx;
    const int* edst = eidx + N_EDGES;
    float* out = (float*)d_out;

    float* ws      = (float*)d_ws;
    float* h_buf   = ws;                         // 6,400,000 f32
    float* act0    = h_buf + 6400000;            // 6,400,000
    float* act1    = act0 + 6400000;             // 6,400,000
    float* asrcb   = act1 + 6400000;             // 400,000
    float* adstb   = asrcb + 400000;             // 400,000
    int*   cnt     = (int*)(adstb + 400000);     // 50,000
    int*   cursor  = cnt + 50000;                // 50,000 (adjacent: one memset)
    int*   row_ptr = cursor + 50000;             // 50,001
    int*   edge_src= row_ptr + 50001;            // 850,000
    int*   gstart  = edge_src + 850000;          // 257

    const int B = 256;
    dim3 blk(B);
    dim3 g_gemm((N_NODES + 63) / 64);
    dim3 g_hist((N_EDGES / 4 + B - 1) / B);
    dim3 g_scat((N_EDGES / 4 + N_NODES + B - 1) / B);
    dim3 g_gather((N_NODES * 64 + B - 1) / B);

    // ---- build CSR (once per call, reused by all 3 layers) ----
    hipMemsetAsync(cnt, 0, 100000 * 4, stream);   // cnt + cursor
    hist_kernel<<<g_hist, blk, 0, stream>>>(edst, cnt);
    scan_kernel<<<dim3(1), dim3(1024), 0, stream>>>(cnt, row_ptr, batch, gstart);
    scatter_kernel<<<g_scat, blk, 0, stream>>>(esrc, edst, row_ptr, cursor, edge_src);

    // ---- Layer 1: Fin=32, F=64, CH=8 ----
    gemm_kernel<32, 64><<<g_gemm, blk, 0, stream>>>(x, W1, h_buf, a_src1, a_dst1,
                                                    asrcb, adstb);
    gat_gather_kernel<8><<<g_gather, blk, 0, stream>>>(row_ptr, edge_src, asrcb, adstb,
                                                       h_buf, b1, act0);

    // ---- Layer 2: Fin=64, F=128, CH=16 ----
    gemm_kernel<64, 128><<<g_gemm, blk, 0, stream>>>(act0, W2, h_buf, a_src2, a_dst2,
                                                     asrcb, adstb);
    gat_gather_kernel<16><<<g_gather, blk, 0, stream>>>(row_ptr, edge_src, asrcb, adstb,
                                                        h_buf, b2, act1);

    // ---- Layer 3: Fin=128, F=128, CH=16 ----
    gemm_kernel<128, 128><<<g_gemm, blk, 0, stream>>>(act1, W3, h_buf, a_src3, a_dst3,
                                                      asrcb, adstb);
    gat_gather_kernel<16><<<g_gather, blk, 0, stream>>>(row_ptr, edge_src, asrcb, adstb,
                                                        h_buf, b3, act0);

    // ---- Pool + head (no atomics) ----
    pool_head_kernel<<<dim3(N_GRAPHS), dim3(512), 0, stream>>>(act0, gstart, fc1_w, fc1_b,
                                                               fc2_w, fc2_b, out);
}

// Round 11
// 350.321 us; speedup vs baseline: 1.1506x; 1.1506x over previous
//
#include <hip/hip_runtime.h>
#include <hip/hip_bf16.h>

#define N_NODES   50000
#define N_EDGES   800000
#define N_TOT     850000   // edges + self loops
#define N_GRAPHS  256
#define HEADS     8
#define NEG_SLOPE 0.2f

// ------- dense GEMM + fused alpha: H = X@W; asrc/adst = <H, a_src/a_dst> ----
template<int FIN, int FOUT>
__global__ __launch_bounds__(256) void gemm_kernel(const float* __restrict__ X,
                                                   const float* __restrict__ W,
                                                   float* __restrict__ H,
                                                   const float* __restrict__ a_src,
                                                   const float* __restrict__ a_dst,
                                                   float* __restrict__ asrc_o,
                                                   float* __restrict__ adst_o) {
    constexpr int KC    = 32;
    constexpr int THR_F = FOUT / 4;        // threads spanning fout (32 or 16)
    constexpr int NPT   = 64 / (256 / THR_F); // nodes per thread (8 or 4)
    constexpr int XS_S  = 68;              // padded node-stride (16B aligned)
    constexpr int CH    = FOUT / 8;        // channels per head
    __shared__ float xs[KC * XS_S];        // [k][node]
    __shared__ float ws[KC * FOUT];        // [k][fout]
    const int t = threadIdx.x;
    const int node0 = blockIdx.x * 64;
    const int fo  = (t % THR_F) * 4;
    const int ndb = (t / THR_F) * NPT;
    float4 acc[NPT];
#pragma unroll
    for (int i = 0; i < NPT; ++i) acc[i] = make_float4(0.f, 0.f, 0.f, 0.f);

    const int xn = t >> 2, ks = (t & 3) * 8;   // staging roles
    for (int kc = 0; kc < FIN; kc += KC) {
        __syncthreads();
        float4 a0 = make_float4(0.f,0.f,0.f,0.f), a1 = a0;
        if (node0 + xn < N_NODES) {
            const float* xp = X + (size_t)(node0 + xn) * FIN + kc + ks;
            a0 = *(const float4*)xp;
            a1 = *(const float4*)(xp + 4);
        }
        xs[(ks + 0) * XS_S + xn] = a0.x;
        xs[(ks + 1) * XS_S + xn] = a0.y;
        xs[(ks + 2) * XS_S + xn] = a0.z;
        xs[(ks + 3) * XS_S + xn] = a0.w;
        xs[(ks + 4) * XS_S + xn] = a1.x;
        xs[(ks + 5) * XS_S + xn] = a1.y;
        xs[(ks + 6) * XS_S + xn] = a1.z;
        xs[(ks + 7) * XS_S + xn] = a1.w;
        constexpr int WF4 = KC * FOUT / 4 / 256;   // float4 per thread (4 or 2)
        const float4* wsrc = (const float4*)(W + (size_t)kc * FOUT);
        float4* wdst = (float4*)ws;
#pragma unroll
        for (int i = 0; i < WF4; ++i) wdst[t * WF4 + i] = wsrc[t * WF4 + i];
        __syncthreads();
#pragma unroll 4
        for (int k = 0; k < KC; ++k) {
            float4 wv = *(const float4*)(ws + k * FOUT + fo);
#pragma unroll
            for (int q = 0; q < NPT / 4; ++q) {
                float4 xv = *(const float4*)(xs + k * XS_S + ndb + q * 4);
                acc[q*4+0].x += xv.x * wv.x; acc[q*4+0].y += xv.x * wv.y;
                acc[q*4+0].z += xv.x * wv.z; acc[q*4+0].w += xv.x * wv.w;
                acc[q*4+1].x += xv.y * wv.x; acc[q*4+1].y += xv.y * wv.y;
                acc[q*4+1].z += xv.y * wv.z; acc[q*4+1].w += xv.y * wv.w;
                acc[q*4+2].x += xv.z * wv.x; acc[q*4+2].y += xv.z * wv.y;
                acc[q*4+2].z += xv.z * wv.z; acc[q*4+2].w += xv.z * wv.w;
                acc[q*4+3].x += xv.w * wv.x; acc[q*4+3].y += xv.w * wv.y;
                acc[q*4+3].z += xv.w * wv.z; acc[q*4+3].w += xv.w * wv.w;
            }
        }
    }
    const int h   = fo / CH;           // head owning this thread's 4 channels
    const float4 asv = *(const float4*)(a_src + h * CH + (fo % CH));
    const float4 adv = *(const float4*)(a_dst + h * CH + (fo % CH));
    constexpr int LPH = CH / 4;        // threads per head (4 or 2)
#pragma unroll
    for (int i = 0; i < NPT; ++i) {
        int row = node0 + ndb + i;
        if (row < N_NODES) *(float4*)(H + (size_t)row * FOUT + fo) = acc[i];
        float s = acc[i].x*asv.x + acc[i].y*asv.y + acc[i].z*asv.z + acc[i].w*asv.w;
        float d = acc[i].x*adv.x + acc[i].y*adv.y + acc[i].z*adv.z + acc[i].w*adv.w;
        s += __shfl_xor(s, 1, 64);
        d += __shfl_xor(d, 1, 64);
        if (LPH == 4) { s += __shfl_xor(s, 2, 64); d += __shfl_xor(d, 2, 64); }
        if ((t & (LPH - 1)) == 0 && row < N_NODES) {
            asrc_o[row * 8 + h] = s;
            adst_o[row * 8 + h] = d;
        }
    }
}

// ---------------- CSR build (counting sort by dst, int4-vectorized) ---------
// self-loops are NOT counted: scan adds +1/node; scatter writes them at slot 0.
__global__ void hist_kernel(const int* __restrict__ edst, int* __restrict__ cnt) {
    int i = blockIdx.x * blockDim.x + threadIdx.x;
    if (i >= N_EDGES / 4) return;
    int4 d4 = ((const int4*)edst)[i];
    atomicAdd(&cnt[d4.x], 1);
    atomicAdd(&cnt[d4.y], 1);
    atomicAdd(&cnt[d4.z], 1);
    atomicAdd(&cnt[d4.w], 1);
}

// multi-block scan, stage 1: per-block prefix (+1 self-loop per node)
__global__ void scan1_kernel(const int* __restrict__ cnt, int* __restrict__ excl,
                             int* __restrict__ bsum) {
    __shared__ int sm[256];
    int t = threadIdx.x;
    int i = blockIdx.x * 256 + t;
    int v = (i < N_NODES) ? (cnt[i] + 1) : 0;   // +1: self loop
    sm[t] = v;
    __syncthreads();
    for (int off = 1; off < 256; off <<= 1) {
        int x = (t >= off) ? sm[t - off] : 0;
        __syncthreads();
        sm[t] += x;
        __syncthreads();
    }
    if (i < N_NODES) excl[i] = sm[t] - v;
    if (t == 255) bsum[blockIdx.x] = sm[255];
}

// stage 2: exclusive scan of the 196 block sums
__global__ void scan2_kernel(int* __restrict__ bsum, int nblk) {
    __shared__ int sm[256];
    int t = threadIdx.x;
    int v = (t < nblk) ? bsum[t] : 0;
    sm[t] = v;
    __syncthreads();
    for (int off = 1; off < 256; off <<= 1) {
        int x = (t >= off) ? sm[t - off] : 0;
        __syncthreads();
        sm[t] += x;
        __syncthreads();
    }
    if (t < nblk) bsum[t] = sm[t] - v;   // exclusive
}

// stage 3: row_ptr = excl + block offset; block 0 also computes gstart
__global__ void scan3_kernel(const int* __restrict__ excl, const int* __restrict__ bsum,
                             int* __restrict__ row_ptr,
                             const int* __restrict__ batch, int* __restrict__ gstart) {
    int i = blockIdx.x * blockDim.x + threadIdx.x;
    if (i < N_NODES) row_ptr[i] = excl[i] + bsum[i >> 8];
    if (i == N_NODES) row_ptr[N_NODES] = N_TOT;
    if (blockIdx.x == 0) {
        int g = threadIdx.x;             // 256 graphs
        int lo = 0, hi = N_NODES;
        while (lo < hi) {                // lower_bound(batch, g)
            int mid = (lo + hi) >> 1;
            if (batch[mid] < g) lo = mid + 1; else hi = mid;
        }
        gstart[g] = lo;
        if (g == 0) gstart[N_GRAPHS] = N_NODES;
    }
}

// real edges (int4, from slot 1) + self loops (slot 0) in one launch
__global__ void scatter_kernel(const int* __restrict__ esrc, const int* __restrict__ edst,
                               const int* __restrict__ row_ptr, int* __restrict__ cursor,
                               int* __restrict__ edge_src) {
    int i = blockIdx.x * blockDim.x + threadIdx.x;
    if (i < N_EDGES / 4) {
        int4 s4 = ((const int4*)esrc)[i];
        int4 d4 = ((const int4*)edst)[i];
        int p;
        p = row_ptr[d4.x] + 1 + atomicAdd(&cursor[d4.x], 1); edge_src[p] = s4.x;
        p = row_ptr[d4.y] + 1 + atomicAdd(&cursor[d4.y], 1); edge_src[p] = s4.y;
        p = row_ptr[d4.z] + 1 + atomicAdd(&cursor[d4.z], 1); edge_src[p] = s4.z;
        p = row_ptr[d4.w] + 1 + atomicAdd(&cursor[d4.w], 1); edge_src[p] = s4.w;
    } else if (i < N_EDGES / 4 + N_NODES) {
        int d = i - N_EDGES / 4;
        edge_src[row_ptr[d]] = d;        // self loop at slot 0
    }
}

// ------- fused gather: softmax (no max-shift; logits O(1), f32-safe) --------
template<int CH>
__global__ __launch_bounds__(256) void gat_gather_kernel(
        const int* __restrict__ row_ptr, const int* __restrict__ edge_src,
        const float* __restrict__ asrc, const float* __restrict__ adst,
        const float* __restrict__ H, const float* __restrict__ bias,
        float* __restrict__ out) {
    constexpr int LPE   = 2 * CH;    // 32 (CH16) or 16 (CH8)
    constexpr int SPLIT = 64 / LPE;  // 2 or 4
    constexpr int LPH   = CH / 4;    // lanes per head (4 or 2)
    constexpr int HS    = 8 * CH;    // floats per row
    const int n = (blockIdx.x * blockDim.x + threadIdx.x) >> 6;
    if (n >= N_NODES) return;
    const int lane = threadIdx.x & 63;
    const int sub = lane / LPE;
    const int li  = lane & (LPE - 1);
    const int h   = li / LPH;
    const int off = h * CH + (li & (LPH - 1)) * 4;   // float offset in row
    const float adst_h = adst[n * 8 + h];
    const int e0 = row_ptr[n], e1 = row_ptr[n + 1];
    float sum = 0.f;
    float4 acc = make_float4(0.f, 0.f, 0.f, 0.f);
    int e = e0 + sub;
    for (; e + 3 * SPLIT < e1; e += 4 * SPLIT) {
        int s0 = edge_src[e];
        int s1 = edge_src[e + SPLIT];
        int s2 = edge_src[e + 2 * SPLIT];
        int s3 = edge_src[e + 3 * SPLIT];
        float l0 = asrc[s0 * 8 + h] + adst_h;
        float l1 = asrc[s1 * 8 + h] + adst_h;
        float l2 = asrc[s2 * 8 + h] + adst_h;
        float l3 = asrc[s3 * 8 + h] + adst_h;
        float4 h0 = *(const float4*)(H + (size_t)s0 * HS + off);
        float4 h1 = *(const float4*)(H + (size_t)s1 * HS + off);
        float4 h2 = *(const float4*)(H + (size_t)s2 * HS + off);
        float4 h3 = *(const float4*)(H + (size_t)s3 * HS + off);
        l0 = l0 > 0.f ? l0 : NEG_SLOPE * l0;
        l1 = l1 > 0.f ? l1 : NEG_SLOPE * l1;
        l2 = l2 > 0.f ? l2 : NEG_SLOPE * l2;
        l3 = l3 > 0.f ? l3 : NEG_SLOPE * l3;
        float w0 = __expf(l0), w1 = __expf(l1), w2 = __expf(l2), w3 = __expf(l3);
        sum += (w0 + w1) + (w2 + w3);
        acc.x += w0 * h0.x + w1 * h1.x + w2 * h2.x + w3 * h3.x;
        acc.y += w0 * h0.y + w1 * h1.y + w2 * h2.y + w3 * h3.y;
        acc.z += w0 * h0.z + w1 * h1.z + w2 * h2.z + w3 * h3.z;
        acc.w += w0 * h0.w + w1 * h1.w + w2 * h2.w + w3 * h3.w;
    }
    for (; e < e1; e += SPLIT) {        // tail
        int s = edge_src[e];
        float l = asrc[s * 8 + h] + adst_h;
        float4 hv = *(const float4*)(H + (size_t)s * HS + off);
        l = l > 0.f ? l : NEG_SLOPE * l;
        float w = __expf(l);
        sum += w;
        acc.x += w * hv.x;
        acc.y += w * hv.y;
        acc.z += w * hv.z;
        acc.w += w * hv.w;
    }
#pragma unroll
    for (int mask = LPE; mask < 64; mask <<= 1) {
        sum   += __shfl_xor(sum, mask, 64);
        acc.x += __shfl_xor(acc.x, mask, 64);
        acc.y += __shfl_xor(acc.y, mask, 64);
        acc.z += __shfl_xor(acc.z, mask, 64);
        acc.w += __shfl_xor(acc.w, mask, 64);
    }
    float inv = 1.0f / (sum + 1e-16f);
    float4 bv = *(const float4*)(bias + off);
    float4 v;
    v.x = acc.x * inv + bv.x;  v.x = v.x > 0.f ? v.x : expm1f(v.x);
    v.y = acc.y * inv + bv.y;  v.y = v.y > 0.f ? v.y : expm1f(v.y);
    v.z = acc.z * inv + bv.z;  v.z = v.z > 0.f ? v.z : expm1f(v.z);
    v.w = acc.w * inv + bv.w;  v.w = v.w > 0.f ? v.w : expm1f(v.w);
    *(float4*)(out + (size_t)n * HS + off) = v;
}

// ---------------- pool + head (sorted batch -> no atomics) ------------------
__global__ __launch_bounds__(512) void pool_head_kernel(
        const float* __restrict__ act, const int* __restrict__ gstart,
        const float* __restrict__ fc1_w, const float* __restrict__ fc1_b,
        const float* __restrict__ fc2_w, const float* __restrict__ fc2_b,
        float* __restrict__ out) {
    int g = blockIdx.x;
    int t = threadIdx.x;
    int f = t & 127, strip = t >> 7;       // 0..3
    int n0 = gstart[g], n1 = gstart[g + 1];
    float s = 0.f;
    for (int n = n0 + strip; n < n1; n += 4) s += act[(size_t)n * 128 + f];
    __shared__ float sm[4][128];
    __shared__ float zz[10];
    sm[strip][f] = s;
    __syncthreads();
    if (strip == 0) {
        float cnt = (float)(n1 - n0);
        cnt = cnt > 1.f ? cnt : 1.f;
        sm[0][f] = (sm[0][f] + sm[1][f] + sm[2][f] + sm[3][f]) / cnt;
    }
    __syncthreads();
    if (t < 10) {
        float z = fc1_b[t];
        for (int q = 0; q < 128; ++q) z += sm[0][q] * fc1_w[q * 10 + t];
        zz[t] = z > 0.f ? z : 0.f;
    }
    __syncthreads();
    if (t == 0) {
        float o = fc2_b[0];
#pragma unroll
        for (int j = 0; j < 10; ++j) o += zz[j] * fc2_w[j];
        out[g] = o;
    }
}

extern "C" void kernel_launch(void* const* d_in, const int* in_sizes, int n_in,
                              void* d_out, int out_size, void* d_ws, size_t ws_size,
                              hipStream_t stream) {
    const float* x      = (const float*)d_in[0];
    const float* W1     = (const float*)d_in[1];
    const float* a_src1 = (const float*)d_in[2];
    const float* a_dst1 = (const float*)d_in[3];
    const float* b1     = (const float*)d_in[4];
    const float* W2     = (const float*)d_in[5];
    const float* a_src2 = (const float*)d_in[6];
    const float* a_dst2 = (const float*)d_in[7];
    const float* b2     = (const float*)d_in[8];
    const float* W3     = (const float*)d_in[9];
    const float* a_src3 = (const float*)d_in[10];
    const float* a_dst3 = (const float*)d_in[11];
    const float* b3     = (const float*)d_in[12];
    const float* fc1_w  = (const float*)d_in[13];
    const float* fc1_b  = (const float*)d_in[14];
    const float* fc2_w  = (const float*)d_in[15];
    const float* fc2_b  = (const float*)d_in[16];
    const int*   eidx   = (const int*)d_in[17];
    const int*   batch  = (const int*)d_in[18];
    const int* esrc = eidx;
    const int* edst = eidx + N_EDGES;
    float* out = (float*)d_out;

    float* ws      = (float*)d_ws;
    float* h_buf   = ws;                         // 6,400,000 f32
    float* act0    = h_buf + 6400000;            // 6,400,000
    float* act1    = act0 + 6400000;             // 6,400,000
    float* asrcb   = act1 + 6400000;             // 400,000
    float* adstb   = asrcb + 400000;             // 400,000
    int*   cnt     = (int*)(adstb + 400000);     // 50,000
    int*   cursor  = cnt + 50000;                // 50,000 (adjacent: one memset)
    int*   excl    = cursor + 50000;             // 50,000
    int*   bsum    = excl + 50000;               // 256
    int*   row_ptr = bsum + 256;                 // 50,001
    int*   edge_src= row_ptr + 50001;            // 850,000
    int*   gstart  = edge_src + 850000;          // 257

    const int B = 256;
    dim3 blk(B);
    dim3 g_gemm((N_NODES + 63) / 64);
    dim3 g_hist((N_EDGES / 4 + B - 1) / B);
    dim3 g_scat((N_EDGES / 4 + N_NODES + B - 1) / B);
    dim3 g_gather((N_NODES * 64 + B - 1) / B);
    const int nblk_scan = (N_NODES + 255) / 256;   // 196

    // ---- build CSR (once per call, reused by all 3 layers) ----
    hipMemsetAsync(cnt, 0, 100000 * 4, stream);   // cnt + cursor
    hist_kernel<<<g_hist, blk, 0, stream>>>(edst, cnt);
    scan1_kernel<<<dim3(nblk_scan), blk, 0, stream>>>(cnt, excl, bsum);
    scan2_kernel<<<dim3(1), blk, 0, stream>>>(bsum, nblk_scan);
    scan3_kernel<<<dim3((N_NODES + B) / B), blk, 0, stream>>>(excl, bsum, row_ptr,
                                                              batch, gstart);
    scatter_kernel<<<g_scat, blk, 0, stream>>>(esrc, edst, row_ptr, cursor, edge_src);

    // ---- Layer 1: Fin=32, F=64, CH=8 ----
    gemm_kernel<32, 64><<<g_gemm, blk, 0, stream>>>(x, W1, h_buf, a_src1, a_dst1,
                                                    asrcb, adstb);
    gat_gather_kernel<8><<<g_gather, blk, 0, stream>>>(row_ptr, edge_src, asrcb, adstb,
                                                       h_buf, b1, act0);

    // ---- Layer 2: Fin=64, F=128, CH=16 ----
    gemm_kernel<64, 128><<<g_gemm, blk, 0, stream>>>(act0, W2, h_buf, a_src2, a_dst2,
                                                     asrcb, adstb);
    gat_gather_kernel<16><<<g_gather, blk, 0, stream>>>(row_ptr, edge_src, asrcb, adstb,
                                                        h_buf, b2, act1);

    // ---- Layer 3: Fin=128, F=128, CH=16 ----
    gemm_kernel<128, 128><<<g_gemm, blk, 0, stream>>>(act1, W3, h_buf, a_src3, a_dst3,
                                                      asrcb, adstb);
    gat_gather_kernel<16><<<g_gather, blk, 0, stream>>>(row_ptr, edge_src, asrcb, adstb,
                                                        h_buf, b3, act0);

    // ---- Pool + head (no atomics) ----
    pool_head_kernel<<<dim3(N_GRAPHS), dim3(512), 0, stream>>>(act0, gstart, fc1_w, fc1_b,
                                                               fc2_w, fc2_b, out);
}

// Round 12
// 319.948 us; speedup vs baseline: 1.2598x; 1.0949x over previous
//
#include <hip/hip_runtime.h>
#include <hip/hip_bf16.h>

#define N_NODES   50000
#define N_EDGES   800000
#define N_TOT     850000   // edges + self loops
#define N_GRAPHS  256
#define HEADS     8
#define NEG_SLOPE 0.2f

// ------- dense GEMM + fused alpha: H = X@W; asrc/adst = <H, a_src/a_dst> ----
template<int FIN, int FOUT>
__global__ __launch_bounds__(256) void gemm_kernel(const float* __restrict__ X,
                                                   const float* __restrict__ W,
                                                   float* __restrict__ H,
                                                   const float* __restrict__ a_src,
                                                   const float* __restrict__ a_dst,
                                                   float* __restrict__ asrc_o,
                                                   float* __restrict__ adst_o) {
    constexpr int KC    = 32;
    constexpr int THR_F = FOUT / 4;        // threads spanning fout (32 or 16)
    constexpr int NPT   = 64 / (256 / THR_F); // nodes per thread (8 or 4)
    constexpr int XS_S  = 68;              // padded node-stride (16B aligned)
    constexpr int CH    = FOUT / 8;        // channels per head
    __shared__ float xs[KC * XS_S];        // [k][node]
    __shared__ float ws[KC * FOUT];        // [k][fout]
    const int t = threadIdx.x;
    const int node0 = blockIdx.x * 64;
    const int fo  = (t % THR_F) * 4;
    const int ndb = (t / THR_F) * NPT;
    float4 acc[NPT];
#pragma unroll
    for (int i = 0; i < NPT; ++i) acc[i] = make_float4(0.f, 0.f, 0.f, 0.f);

    const int xn = t >> 2, ks = (t & 3) * 8;   // staging roles
    for (int kc = 0; kc < FIN; kc += KC) {
        __syncthreads();
        float4 a0 = make_float4(0.f,0.f,0.f,0.f), a1 = a0;
        if (node0 + xn < N_NODES) {
            const float* xp = X + (size_t)(node0 + xn) * FIN + kc + ks;
            a0 = *(const float4*)xp;
            a1 = *(const float4*)(xp + 4);
        }
        xs[(ks + 0) * XS_S + xn] = a0.x;
        xs[(ks + 1) * XS_S + xn] = a0.y;
        xs[(ks + 2) * XS_S + xn] = a0.z;
        xs[(ks + 3) * XS_S + xn] = a0.w;
        xs[(ks + 4) * XS_S + xn] = a1.x;
        xs[(ks + 5) * XS_S + xn] = a1.y;
        xs[(ks + 6) * XS_S + xn] = a1.z;
        xs[(ks + 7) * XS_S + xn] = a1.w;
        constexpr int WF4 = KC * FOUT / 4 / 256;   // float4 per thread (4 or 2)
        const float4* wsrc = (const float4*)(W + (size_t)kc * FOUT);
        float4* wdst = (float4*)ws;
#pragma unroll
        for (int i = 0; i < WF4; ++i) wdst[t * WF4 + i] = wsrc[t * WF4 + i];
        __syncthreads();
#pragma unroll 4
        for (int k = 0; k < KC; ++k) {
            float4 wv = *(const float4*)(ws + k * FOUT + fo);
#pragma unroll
            for (int q = 0; q < NPT / 4; ++q) {
                float4 xv = *(const float4*)(xs + k * XS_S + ndb + q * 4);
                acc[q*4+0].x += xv.x * wv.x; acc[q*4+0].y += xv.x * wv.y;
                acc[q*4+0].z += xv.x * wv.z; acc[q*4+0].w += xv.x * wv.w;
                acc[q*4+1].x += xv.y * wv.x; acc[q*4+1].y += xv.y * wv.y;
                acc[q*4+1].z += xv.y * wv.z; acc[q*4+1].w += xv.y * wv.w;
                acc[q*4+2].x += xv.z * wv.x; acc[q*4+2].y += xv.z * wv.y;
                acc[q*4+2].z += xv.z * wv.z; acc[q*4+2].w += xv.z * wv.w;
                acc[q*4+3].x += xv.w * wv.x; acc[q*4+3].y += xv.w * wv.y;
                acc[q*4+3].z += xv.w * wv.z; acc[q*4+3].w += xv.w * wv.w;
            }
        }
    }
    const int h   = fo / CH;           // head owning this thread's 4 channels
    const float4 asv = *(const float4*)(a_src + h * CH + (fo % CH));
    const float4 adv = *(const float4*)(a_dst + h * CH + (fo % CH));
    constexpr int LPH = CH / 4;        // threads per head (4 or 2)
#pragma unroll
    for (int i = 0; i < NPT; ++i) {
        int row = node0 + ndb + i;
        if (row < N_NODES) *(float4*)(H + (size_t)row * FOUT + fo) = acc[i];
        float s = acc[i].x*asv.x + acc[i].y*asv.y + acc[i].z*asv.z + acc[i].w*asv.w;
        float d = acc[i].x*adv.x + acc[i].y*adv.y + acc[i].z*adv.z + acc[i].w*adv.w;
        s += __shfl_xor(s, 1, 64);
        d += __shfl_xor(d, 1, 64);
        if (LPH == 4) { s += __shfl_xor(s, 2, 64); d += __shfl_xor(d, 2, 64); }
        if ((t & (LPH - 1)) == 0 && row < N_NODES) {
            asrc_o[row * 8 + h] = s;
            adst_o[row * 8 + h] = d;
        }
    }
}

// ---------------- CSR build (counting sort by dst, int4-vectorized) ---------
// hist also records each edge's within-row slot -> scatter needs NO atomics.
// self-loops are NOT counted: scan adds +1/node; scatter writes them at slot 0.
__global__ void hist_kernel(const int* __restrict__ edst, int* __restrict__ cnt,
                            int* __restrict__ slot) {
    int i = blockIdx.x * blockDim.x + threadIdx.x;
    if (i >= N_EDGES / 4) return;
    int4 d4 = ((const int4*)edst)[i];
    int4 sl;
    sl.x = atomicAdd(&cnt[d4.x], 1);
    sl.y = atomicAdd(&cnt[d4.y], 1);
    sl.z = atomicAdd(&cnt[d4.z], 1);
    sl.w = atomicAdd(&cnt[d4.w], 1);
    ((int4*)slot)[i] = sl;               // coalesced
}

// multi-block scan, stage 1: per-block prefix (+1 self-loop per node)
__global__ void scan1_kernel(const int* __restrict__ cnt, int* __restrict__ excl,
                             int* __restrict__ bsum) {
    __shared__ int sm[256];
    int t = threadIdx.x;
    int i = blockIdx.x * 256 + t;
    int v = (i < N_NODES) ? (cnt[i] + 1) : 0;   // +1: self loop
    sm[t] = v;
    __syncthreads();
    for (int off = 1; off < 256; off <<= 1) {
        int x = (t >= off) ? sm[t - off] : 0;
        __syncthreads();
        sm[t] += x;
        __syncthreads();
    }
    if (i < N_NODES) excl[i] = sm[t] - v;
    if (t == 255) bsum[blockIdx.x] = sm[255];
}

// stage 2 fused into stage 3: each block scans the 196 block sums in LDS,
// takes its own exclusive offset; block 0 also computes gstart.
#define NBLK_SCAN 196
__global__ void scan3_kernel(const int* __restrict__ excl, const int* __restrict__ bsum,
                             int* __restrict__ row_ptr,
                             const int* __restrict__ batch, int* __restrict__ gstart) {
    __shared__ int sm[256];
    __shared__ int blkoff;
    int t = threadIdx.x;
    int bx = blockIdx.x;
    int v = (t < NBLK_SCAN) ? bsum[t] : 0;
    sm[t] = v;
    __syncthreads();
    for (int off = 1; off < 256; off <<= 1) {
        int x = (t >= off) ? sm[t - off] : 0;
        __syncthreads();
        sm[t] += x;
        __syncthreads();
    }
    if (t == 0) blkoff = (bx < NBLK_SCAN) ? (sm[bx] - bsum[bx]) : 0;  // exclusive
    __syncthreads();
    int i = bx * 256 + t;
    if (i < N_NODES) row_ptr[i] = excl[i] + blkoff;
    if (i == N_NODES) row_ptr[N_NODES] = N_TOT;
    if (bx == 0) {
        int g = t;                       // 256 graphs
        int lo = 0, hi = N_NODES;
        while (lo < hi) {                // lower_bound(batch, g)
            int mid = (lo + hi) >> 1;
            if (batch[mid] < g) lo = mid + 1; else hi = mid;
        }
        gstart[g] = lo;
        if (g == 0) gstart[N_GRAPHS] = N_NODES;
    }
}

// real edges (int4, slot-indexed, NO atomics) + self loops (slot 0)
__global__ void scatter_kernel(const int* __restrict__ esrc, const int* __restrict__ edst,
                               const int* __restrict__ row_ptr,
                               const int* __restrict__ slot,
                               int* __restrict__ edge_src) {
    int i = blockIdx.x * blockDim.x + threadIdx.x;
    if (i < N_EDGES / 4) {
        int4 s4 = ((const int4*)esrc)[i];
        int4 d4 = ((const int4*)edst)[i];
        int4 sl = ((const int4*)slot)[i];
        edge_src[row_ptr[d4.x] + 1 + sl.x] = s4.x;
        edge_src[row_ptr[d4.y] + 1 + sl.y] = s4.y;
        edge_src[row_ptr[d4.z] + 1 + sl.z] = s4.z;
        edge_src[row_ptr[d4.w] + 1 + sl.w] = s4.w;
    } else if (i < N_EDGES / 4 + N_NODES) {
        int d = i - N_EDGES / 4;
        edge_src[row_ptr[d]] = d;        // self loop at slot 0
    }
}

// ------- fused gather: softmax (no max-shift; logits O(1), f32-safe) --------
template<int CH>
__global__ __launch_bounds__(256) void gat_gather_kernel(
        const int* __restrict__ row_ptr, const int* __restrict__ edge_src,
        const float* __restrict__ asrc, const float* __restrict__ adst,
        const float* __restrict__ H, const float* __restrict__ bias,
        float* __restrict__ out) {
    constexpr int LPE   = 2 * CH;    // 32 (CH16) or 16 (CH8)
    constexpr int SPLIT = 64 / LPE;  // 2 or 4
    constexpr int LPH   = CH / 4;    // lanes per head (4 or 2)
    constexpr int HS    = 8 * CH;    // floats per row
    const int n = (blockIdx.x * blockDim.x + threadIdx.x) >> 6;
    if (n >= N_NODES) return;
    const int lane = threadIdx.x & 63;
    const int sub = lane / LPE;
    const int li  = lane & (LPE - 1);
    const int h   = li / LPH;
    const int off = h * CH + (li & (LPH - 1)) * 4;   // float offset in row
    const float adst_h = adst[n * 8 + h];
    const int e0 = row_ptr[n], e1 = row_ptr[n + 1];
    float sum = 0.f;
    float4 acc = make_float4(0.f, 0.f, 0.f, 0.f);
    int e = e0 + sub;
    for (; e + 3 * SPLIT < e1; e += 4 * SPLIT) {
        int s0 = edge_src[e];
        int s1 = edge_src[e + SPLIT];
        int s2 = edge_src[e + 2 * SPLIT];
        int s3 = edge_src[e + 3 * SPLIT];
        float l0 = asrc[s0 * 8 + h] + adst_h;
        float l1 = asrc[s1 * 8 + h] + adst_h;
        float l2 = asrc[s2 * 8 + h] + adst_h;
        float l3 = asrc[s3 * 8 + h] + adst_h;
        float4 h0 = *(const float4*)(H + (size_t)s0 * HS + off);
        float4 h1 = *(const float4*)(H + (size_t)s1 * HS + off);
        float4 h2 = *(const float4*)(H + (size_t)s2 * HS + off);
        float4 h3 = *(const float4*)(H + (size_t)s3 * HS + off);
        l0 = l0 > 0.f ? l0 : NEG_SLOPE * l0;
        l1 = l1 > 0.f ? l1 : NEG_SLOPE * l1;
        l2 = l2 > 0.f ? l2 : NEG_SLOPE * l2;
        l3 = l3 > 0.f ? l3 : NEG_SLOPE * l3;
        float w0 = __expf(l0), w1 = __expf(l1), w2 = __expf(l2), w3 = __expf(l3);
        sum += (w0 + w1) + (w2 + w3);
        acc.x += w0 * h0.x + w1 * h1.x + w2 * h2.x + w3 * h3.x;
        acc.y += w0 * h0.y + w1 * h1.y + w2 * h2.y + w3 * h3.y;
        acc.z += w0 * h0.z + w1 * h1.z + w2 * h2.z + w3 * h3.z;
        acc.w += w0 * h0.w + w1 * h1.w + w2 * h2.w + w3 * h3.w;
    }
    for (; e < e1; e += SPLIT) {        // tail
        int s = edge_src[e];
        float l = asrc[s * 8 + h] + adst_h;
        float4 hv = *(const float4*)(H + (size_t)s * HS + off);
        l = l > 0.f ? l : NEG_SLOPE * l;
        float w = __expf(l);
        sum += w;
        acc.x += w * hv.x;
        acc.y += w * hv.y;
        acc.z += w * hv.z;
        acc.w += w * hv.w;
    }
#pragma unroll
    for (int mask = LPE; mask < 64; mask <<= 1) {
        sum   += __shfl_xor(sum, mask, 64);
        acc.x += __shfl_xor(acc.x, mask, 64);
        acc.y += __shfl_xor(acc.y, mask, 64);
        acc.z += __shfl_xor(acc.z, mask, 64);
        acc.w += __shfl_xor(acc.w, mask, 64);
    }
    float inv = 1.0f / (sum + 1e-16f);
    float4 bv = *(const float4*)(bias + off);
    float4 v;
    v.x = acc.x * inv + bv.x;  v.x = v.x > 0.f ? v.x : expm1f(v.x);
    v.y = acc.y * inv + bv.y;  v.y = v.y > 0.f ? v.y : expm1f(v.y);
    v.z = acc.z * inv + bv.z;  v.z = v.z > 0.f ? v.z : expm1f(v.z);
    v.w = acc.w * inv + bv.w;  v.w = v.w > 0.f ? v.w : expm1f(v.w);
    *(float4*)(out + (size_t)n * HS + off) = v;
}

// ---------------- pool + head (sorted batch -> no atomics) ------------------
__global__ __launch_bounds__(512) void pool_head_kernel(
        const float* __restrict__ act, const int* __restrict__ gstart,
        const float* __restrict__ fc1_w, const float* __restrict__ fc1_b,
        const float* __restrict__ fc2_w, const float* __restrict__ fc2_b,
        float* __restrict__ out) {
    int g = blockIdx.x;
    int t = threadIdx.x;
    int f = t & 127, strip = t >> 7;       // 0..3
    int n0 = gstart[g], n1 = gstart[g + 1];
    float s = 0.f;
    for (int n = n0 + strip; n < n1; n += 4) s += act[(size_t)n * 128 + f];
    __shared__ float sm[4][128];
    __shared__ float zz[10];
    sm[strip][f] = s;
    __syncthreads();
    if (strip == 0) {
        float cnt = (float)(n1 - n0);
        cnt = cnt > 1.f ? cnt : 1.f;
        sm[0][f] = (sm[0][f] + sm[1][f] + sm[2][f] + sm[3][f]) / cnt;
    }
    __syncthreads();
    if (t < 10) {
        float z = fc1_b[t];
        for (int q = 0; q < 128; ++q) z += sm[0][q] * fc1_w[q * 10 + t];
        zz[t] = z > 0.f ? z : 0.f;
    }
    __syncthreads();
    if (t == 0) {
        float o = fc2_b[0];
#pragma unroll
        for (int j = 0; j < 10; ++j) o += zz[j] * fc2_w[j];
        out[g] = o;
    }
}

extern "C" void kernel_launch(void* const* d_in, const int* in_sizes, int n_in,
                              void* d_out, int out_size, void* d_ws, size_t ws_size,
                              hipStream_t stream) {
    const float* x      = (const float*)d_in[0];
    const float* W1     = (const float*)d_in[1];
    const float* a_src1 = (const float*)d_in[2];
    const float* a_dst1 = (const float*)d_in[3];
    const float* b1     = (const float*)d_in[4];
    const float* W2     = (const float*)d_in[5];
    const float* a_src2 = (const float*)d_in[6];
    const float* a_dst2 = (const float*)d_in[7];
    const float* b2     = (const float*)d_in[8];
    const float* W3     = (const float*)d_in[9];
    const float* a_src3 = (const float*)d_in[10];
    const float* a_dst3 = (const float*)d_in[11];
    const float* b3     = (const float*)d_in[12];
    const float* fc1_w  = (const float*)d_in[13];
    const float* fc1_b  = (const float*)d_in[14];
    const float* fc2_w  = (const float*)d_in[15];
    const float* fc2_b  = (const float*)d_in[16];
    const int*   eidx   = (const int*)d_in[17];
    const int*   batch  = (const int*)d_in[18];
    const int* esrc = eidx;
    const int* edst = eidx + N_EDGES;
    float* out = (float*)d_out;

    float* ws      = (float*)d_ws;
    float* h_buf   = ws;                         // 6,400,000 f32
    float* act0    = h_buf + 6400000;            // 6,400,000
    float* act1    = act0 + 6400000;             // 6,400,000
    float* asrcb   = act1 + 6400000;             // 400,000
    float* adstb   = asrcb + 400000;             // 400,000
    int*   cnt     = (int*)(adstb + 400000);     // 50,000
    int*   excl    = cnt + 50000;                // 50,000
    int*   bsum    = excl + 50000;               // 256
    int*   row_ptr = bsum + 256;                 // 50,001
    int*   edge_src= row_ptr + 50001;            // 850,000
    int*   slot    = edge_src + 850000;          // 800,000
    int*   gstart  = slot + 800000;              // 257

    const int B = 256;
    dim3 blk(B);
    dim3 g_gemm((N_NODES + 63) / 64);
    dim3 g_hist((N_EDGES / 4 + B - 1) / B);
    dim3 g_scat((N_EDGES / 4 + N_NODES + B - 1) / B);
    dim3 g_gather((N_NODES * 64 + B - 1) / B);

    // ---- build CSR (once per call, reused by all 3 layers) ----
    hipMemsetAsync(cnt, 0, 50000 * 4, stream);
    hist_kernel<<<g_hist, blk, 0, stream>>>(edst, cnt, slot);
    scan1_kernel<<<dim3(NBLK_SCAN), blk, 0, stream>>>(cnt, excl, bsum);
    scan3_kernel<<<dim3((N_NODES + B) / B), blk, 0, stream>>>(excl, bsum, row_ptr,
                                                              batch, gstart);
    scatter_kernel<<<g_scat, blk, 0, stream>>>(esrc, edst, row_ptr, slot, edge_src);

    // ---- Layer 1: Fin=32, F=64, CH=8 ----
    gemm_kernel<32, 64><<<g_gemm, blk, 0, stream>>>(x, W1, h_buf, a_src1, a_dst1,
                                                    asrcb, adstb);
    gat_gather_kernel<8><<<g_gather, blk, 0, stream>>>(row_ptr, edge_src, asrcb, adstb,
                                                       h_buf, b1, act0);

    // ---- Layer 2: Fin=64, F=128, CH=16 ----
    gemm_kernel<64, 128><<<g_gemm, blk, 0, stream>>>(act0, W2, h_buf, a_src2, a_dst2,
                                                     asrcb, adstb);
    gat_gather_kernel<16><<<g_gather, blk, 0, stream>>>(row_ptr, edge_src, asrcb, adstb,
                                                        h_buf, b2, act1);

    // ---- Layer 3: Fin=128, F=128, CH=16 ----
    gemm_kernel<128, 128><<<g_gemm, blk, 0, stream>>>(act1, W3, h_buf, a_src3, a_dst3,
                                                      asrcb, adstb);
    gat_gather_kernel<16><<<g_gather, blk, 0, stream>>>(row_ptr, edge_src, asrcb, adstb,
                                                        h_buf, b3, act0);

    // ---- Pool + head (no atomics) ----
    pool_head_kernel<<<dim3(N_GRAPHS), dim3(512), 0, stream>>>(act0, gstart, fc1_w, fc1_b,
                                                               fc2_w, fc2_b, out);
}